// Round 11
// baseline (160.582 us; speedup 1.0000x reference)
//
#include <hip/hip_runtime.h>
#include <hip/hip_fp16.h>

#define T_DIM   12
#define N_NODES 10000
#define F_IN    32
#define H_DIM   64
#define NCH     3            // t-chunks
#define TC      4            // timesteps per chunk
#define CHROW   (TC * F_IN)  // fp16/fp32 elements per node per chunk = 128
#define NGRP    (N_NODES / 16)
#define NTASK   (NCH * NGRP)
#define NROWS   (NCH * N_NODES * TC)  // 120000 (n,t) rows
#define MROWS   128                   // rows per mlp block
#define NREP    4                     // atomic replicas per node

#define CNT_SHIFT 40
#define FIX_SCALE 1048576.0f          // 2^20
#define FIX_MASK  ((1ull << CNT_SHIFT) - 1)

// ------------------------------------------------ zero packed counters (4 replicas)
__global__ void zero_kernel(uint4* __restrict__ p, int n16) {
    int i = blockIdx.x * blockDim.x + threadIdx.x;
    if (i < n16) p[i] = make_uint4(0, 0, 0, 0);
}

// ------------------------------------------------ fused: replicated packed degree+count atomic
// (1 atomic/edge to packed[(e&3)*N + c]; return value = within-replica position) and
// x fp32 [t][n][f] -> xh fp16 chunked convert
__global__ void deg_hist_conv_kernel(const int* __restrict__ col,
                                     const float* __restrict__ w,
                                     unsigned long long* __restrict__ packed,
                                     unsigned int* __restrict__ posE, int E, int eb,
                                     const float* __restrict__ x,
                                     __half* __restrict__ xh) {
    int b = blockIdx.x;
    if (b < eb) {
        int e = b * 256 + threadIdx.x;
        if (e >= E) return;
        int c = col[e];
        unsigned long long fx = (unsigned long long)(w[e] * FIX_SCALE + 0.5f);
        unsigned long long old =
            atomicAdd(&packed[(size_t)(e & (NREP - 1)) * N_NODES + c], (1ull << CNT_SHIFT) | fx);
        posE[e] = (unsigned int)(old >> CNT_SHIFT);
    } else {
        int task = (b - eb) * 4 + (threadIdx.x >> 6);
        if (task >= NTASK) return;
        int l  = threadIdx.x & 63;
        int ch = task / NGRP;
        int ng = task - ch * NGRP;
        int n  = ng * 16 + (l >> 2);
        int t  = ch * TC + (l & 3);
        const float4* xp = (const float4*)(x + ((size_t)t * N_NODES + n) * F_IN);
        union { uint32_t u[16]; uint4 q[4]; } pk;
#pragma unroll
        for (int i = 0; i < 8; i++) {
            float4 v = xp[i];
            __half2 h0 = __floats2half2_rn(v.x, v.y);
            __half2 h1 = __floats2half2_rn(v.z, v.w);
            pk.u[2 * i]     = *(uint32_t*)&h0;
            pk.u[2 * i + 1] = *(uint32_t*)&h1;
        }
        uint4* dp = (uint4*)(xh + ((size_t)ch * N_NODES * TC + ng * 64 + l) * F_IN);
#pragma unroll
        for (int i = 0; i < 4; i++) dp[i] = pk.q[i];
    }
}

// ------------------------------------------------ single-block scan: 4 replicas -> rowptr,
// per-replica bases base[r][c], and dinv. Counts cached packed 4x8-bit between passes.
__global__ __launch_bounds__(1024) void scan_kernel(const unsigned long long* __restrict__ packed,
                                                    int* __restrict__ rowptr,
                                                    int* __restrict__ base,
                                                    float* __restrict__ dinv, int n) {
    __shared__ int part[1024];
    int tid = threadIdx.x;
    const int per = (n + 1023) / 1024;
    int bidx = tid * per;
    unsigned int cpack[10];     // per-node 4 counts, 8 bits each (per <= 10)
    int s = 0;
    for (int i = 0; i < per; i++) {
        int idx = bidx + i;
        if (idx < n) {
            unsigned long long p0 = packed[idx];
            unsigned long long p1 = packed[(size_t)N_NODES + idx];
            unsigned long long p2 = packed[(size_t)2 * N_NODES + idx];
            unsigned long long p3 = packed[(size_t)3 * N_NODES + idx];
            unsigned int c0 = (unsigned int)(p0 >> CNT_SHIFT);
            unsigned int c1 = (unsigned int)(p1 >> CNT_SHIFT);
            unsigned int c2 = (unsigned int)(p2 >> CNT_SHIFT);
            unsigned int c3 = (unsigned int)(p3 >> CNT_SHIFT);
            cpack[i] = c0 | (c1 << 8) | (c2 << 16) | (c3 << 24);
            s += (int)(c0 + c1 + c2 + c3);
            float deg = (float)((p0 & FIX_MASK) + (p1 & FIX_MASK) + (p2 & FIX_MASK) + (p3 & FIX_MASK))
                        * (1.0f / FIX_SCALE);
            dinv[idx] = deg > 0.f ? rsqrtf(deg) : 0.f;
        } else cpack[i] = 0;
    }
    part[tid] = s;
    __syncthreads();
    for (int off = 1; off < 1024; off <<= 1) {
        int v = 0;
        if (tid >= off) v = part[tid - off];
        __syncthreads();
        if (tid >= off) part[tid] += v;
        __syncthreads();
    }
    int run = (tid == 0) ? 0 : part[tid - 1];
    for (int i = 0; i < per; i++) {
        int idx = bidx + i;
        if (idx < n) {
            unsigned int cp = cpack[i];
            int c0 = cp & 255, c1 = (cp >> 8) & 255, c2 = (cp >> 16) & 255, c3 = cp >> 24;
            rowptr[idx] = run;
            base[idx]                 = run;
            base[N_NODES + idx]       = run + c0;
            base[2 * N_NODES + idx]   = run + c0 + c1;
            base[3 * N_NODES + idx]   = run + c0 + c1 + c2;
            run += c0 + c1 + c2 + c3;
        }
    }
    if (tid == 1023) rowptr[n] = part[1023];
}

// ------------------------------------------------ fill: ATOMIC-FREE bucket placement
__global__ void fill_kernel(const int* __restrict__ row,
                            const int* __restrict__ col,
                            const float* __restrict__ w,
                            const float* __restrict__ dinv,
                            const int* __restrict__ base,
                            const unsigned int* __restrict__ posE,
                            int2* __restrict__ edge_s, int E) {
    int e = blockIdx.x * blockDim.x + threadIdx.x;
    if (e >= E) return;
    int r = row[e];
    int c = col[e];
    float nw = dinv[r] * w[e] * dinv[c];
    int pos = base[(size_t)(e & (NREP - 1)) * N_NODES + c] + (int)posE[e];
    edge_s[pos] = make_int2(r, __float_as_int(nw));
}

// ------------------------------------------------ 64-lane-per-node single-pass gather.
// Two 32-lane halves split the edge list (stride 2), combine via shfl_xor(32).
// TANH=false: write fp32 chunked [ch][n][tc][f]. TANH=true: tanh(acc+bias) -> [t][n][f].
template <bool TANH>
__global__ __launch_bounds__(256) void gather64_kernel(const int* __restrict__ rowptr,
                                                       const int2* __restrict__ edge_s,
                                                       const __half* __restrict__ yh,
                                                       const float* __restrict__ bias,
                                                       float* __restrict__ outp, int n) {
    int c = blockIdx.x * 4 + (threadIdx.x >> 6);
    if (c >= n) return;
    int l    = threadIdx.x & 63;
    int half = l >> 5;
    int l32  = l & 31;          // tc = l32>>3, f-quad = l32&7 -> fp16 offset 4*l32

    int beg = rowptr[c], end = rowptr[c + 1];
    const __half* base = yh + 4 * l32;
    const size_t cstep = (size_t)N_NODES * CHROW;

    float4 a0 = {0.f, 0.f, 0.f, 0.f};
    float4 a1 = {0.f, 0.f, 0.f, 0.f};
    float4 a2 = {0.f, 0.f, 0.f, 0.f};

#pragma unroll 8
    for (int e = beg + half; e < end; e += 2) {
        int2 ed = edge_s[e];
        float nw = __int_as_float(ed.y);
        const __half* p = base + (size_t)ed.x * CHROW;
        uint2 u0 = *(const uint2*)(p);
        uint2 u1 = *(const uint2*)(p + cstep);
        uint2 u2 = *(const uint2*)(p + 2 * cstep);
        float2 f00 = __half22float2(*(__half2*)&u0.x), f01 = __half22float2(*(__half2*)&u0.y);
        float2 f10 = __half22float2(*(__half2*)&u1.x), f11 = __half22float2(*(__half2*)&u1.y);
        float2 f20 = __half22float2(*(__half2*)&u2.x), f21 = __half22float2(*(__half2*)&u2.y);
        a0.x = fmaf(f00.x, nw, a0.x); a0.y = fmaf(f00.y, nw, a0.y);
        a0.z = fmaf(f01.x, nw, a0.z); a0.w = fmaf(f01.y, nw, a0.w);
        a1.x = fmaf(f10.x, nw, a1.x); a1.y = fmaf(f10.y, nw, a1.y);
        a1.z = fmaf(f11.x, nw, a1.z); a1.w = fmaf(f11.y, nw, a1.w);
        a2.x = fmaf(f20.x, nw, a2.x); a2.y = fmaf(f20.y, nw, a2.y);
        a2.z = fmaf(f21.x, nw, a2.z); a2.w = fmaf(f21.y, nw, a2.w);
    }

    a0.x += __shfl_xor(a0.x, 32); a0.y += __shfl_xor(a0.y, 32);
    a0.z += __shfl_xor(a0.z, 32); a0.w += __shfl_xor(a0.w, 32);
    a1.x += __shfl_xor(a1.x, 32); a1.y += __shfl_xor(a1.y, 32);
    a1.z += __shfl_xor(a1.z, 32); a1.w += __shfl_xor(a1.w, 32);
    a2.x += __shfl_xor(a2.x, 32); a2.y += __shfl_xor(a2.y, 32);
    a2.z += __shfl_xor(a2.z, 32); a2.w += __shfl_xor(a2.w, 32);

    if (TANH) {
        float4 b4 = *(const float4*)(bias + 4 * (l32 & 7));
        if (half == 0) {
            a0.x = tanhf(a0.x + b4.x); a0.y = tanhf(a0.y + b4.y);
            a0.z = tanhf(a0.z + b4.z); a0.w = tanhf(a0.w + b4.w);
            a1.x = tanhf(a1.x + b4.x); a1.y = tanhf(a1.y + b4.y);
            a1.z = tanhf(a1.z + b4.z); a1.w = tanhf(a1.w + b4.w);
            int t0 = (l32 >> 3);
            float* op0 = outp + ((size_t)t0 * N_NODES + c) * F_IN + 4 * (l32 & 7);
            *(float4*)(op0)                               = a0;
            *(float4*)(op0 + (size_t)TC * N_NODES * F_IN) = a1;
        } else {
            a2.x = tanhf(a2.x + b4.x); a2.y = tanhf(a2.y + b4.y);
            a2.z = tanhf(a2.z + b4.z); a2.w = tanhf(a2.w + b4.w);
            int t2 = 2 * TC + (l32 >> 3);
            float* op2 = outp + ((size_t)t2 * N_NODES + c) * F_IN + 4 * (l32 & 7);
            *(float4*)op2 = a2;
        }
    } else {
        float* op = outp + (size_t)c * CHROW + 4 * l32;
        const size_t ostep = (size_t)N_NODES * CHROW;
        if (half == 0) {
            *(float4*)(op)         = a0;
            *(float4*)(op + ostep) = a1;
        } else {
            *(float4*)(op + 2 * ostep) = a2;
        }
    }
}

// ------------------------------------------------ fused MLP: register-blocked tile GEMM
__global__ __launch_bounds__(128) void mlp_kernel(const float* __restrict__ aggx,
                                                  const float* __restrict__ W1g,
                                                  const float* __restrict__ b1,
                                                  const float* __restrict__ W2g,
                                                  __half* __restrict__ y2h) {
    __shared__ float W1s[F_IN * H_DIM];
    __shared__ float W2s[H_DIM * F_IN];
    __shared__ float b1s[H_DIM];
    __shared__ float xs[MROWS][F_IN + 1];
    __shared__ float hs[MROWS][H_DIM + 1];

    int tid = threadIdx.x;
    for (int i = tid; i < F_IN * H_DIM; i += 128) { W1s[i] = W1g[i]; W2s[i] = W2g[i]; }
    if (tid < H_DIM) b1s[tid] = b1[tid];

    size_t row0 = (size_t)blockIdx.x * MROWS;
    const float4* src = (const float4*)(aggx + row0 * F_IN);
    for (int i = tid; i < MROWS * (F_IN / 4); i += 128) {
        float4 v = src[i];
        int r = i >> 3, q = (i & 7) * 4;
        xs[r][q + 0] = v.x; xs[r][q + 1] = v.y; xs[r][q + 2] = v.z; xs[r][q + 3] = v.w;
    }
    __syncthreads();

    int rg = tid >> 2;
    int cg = tid & 3;
    int r0 = 4 * rg;

    {
        int c0 = 16 * cg;
        float acc[4][16];
#pragma unroll
        for (int j = 0; j < 16; j++) {
            float b = b1s[c0 + j];
#pragma unroll
            for (int rr = 0; rr < 4; rr++) acc[rr][j] = b;
        }
#pragma unroll 8
        for (int k = 0; k < F_IN; k++) {
            float xr[4];
#pragma unroll
            for (int rr = 0; rr < 4; rr++) xr[rr] = xs[r0 + rr][k];
#pragma unroll
            for (int j = 0; j < 16; j++) {
                float wv = W1s[k * H_DIM + c0 + j];
#pragma unroll
                for (int rr = 0; rr < 4; rr++) acc[rr][j] = fmaf(xr[rr], wv, acc[rr][j]);
            }
        }
#pragma unroll
        for (int rr = 0; rr < 4; rr++)
#pragma unroll
            for (int j = 0; j < 16; j++)
                hs[r0 + rr][c0 + j] = fmaxf(acc[rr][j], 0.f);
    }
    __syncthreads();

    {
        int d0 = 8 * cg;
        float acc[4][8];
#pragma unroll
        for (int rr = 0; rr < 4; rr++)
#pragma unroll
            for (int j = 0; j < 8; j++) acc[rr][j] = 0.f;
#pragma unroll 8
        for (int k = 0; k < H_DIM; k++) {
            float hr[4];
#pragma unroll
            for (int rr = 0; rr < 4; rr++) hr[rr] = hs[r0 + rr][k];
#pragma unroll
            for (int j = 0; j < 8; j++) {
                float wv = W2s[k * F_IN + d0 + j];
#pragma unroll
                for (int rr = 0; rr < 4; rr++) acc[rr][j] = fmaf(hr[rr], wv, acc[rr][j]);
            }
        }
#pragma unroll
        for (int rr = 0; rr < 4; rr++) {
            union { uint32_t u[4]; uint4 q; } pk;
#pragma unroll
            for (int i = 0; i < 4; i++) {
                __half2 hh = __floats2half2_rn(acc[rr][2 * i], acc[rr][2 * i + 1]);
                pk.u[i] = *(uint32_t*)&hh;
            }
            *(uint4*)(y2h + (row0 + r0 + rr) * F_IN + d0) = pk.q;
        }
    }
}

// ----------------------------------------------------------------
extern "C" void kernel_launch(void* const* d_in, const int* in_sizes, int n_in,
                              void* d_out, int out_size, void* d_ws, size_t ws_size,
                              hipStream_t stream) {
    const float* x  = (const float*)d_in[0];
    const int*   ei = (const int*)d_in[1];
    const float* w  = (const float*)d_in[2];
    // d_in[3] = missing_mask (unused)
    const float* W1 = (const float*)d_in[4];
    const float* b1 = (const float*)d_in[5];
    const float* W2 = (const float*)d_in[6];
    const float* b2 = (const float*)d_in[7];
    float* out = (float*)d_out;

    const int E = in_sizes[1] / 2;
    const int* row = ei;
    const int* col = ei + E;

    char* ws = (char*)d_ws;
    size_t off = 0;
    auto alloc = [&](size_t bytes) { void* p = ws + off; off += (bytes + 255) & ~(size_t)255; return p; };
    unsigned long long* packed = (unsigned long long*)alloc((size_t)NREP * N_NODES * sizeof(unsigned long long));
    unsigned int* posE = (unsigned int*)alloc((size_t)E * sizeof(unsigned int));
    int*    rowptr = (int*)   alloc((N_NODES + 1) * sizeof(int));
    int*    basep  = (int*)   alloc((size_t)NREP * N_NODES * sizeof(int));
    float*  dinv   = (float*) alloc(N_NODES * sizeof(float));
    int2*   edge_s = (int2*)  alloc((size_t)E * sizeof(int2));
    __half* xh     = (__half*)alloc((size_t)NROWS * F_IN * sizeof(__half));
    __half* y2h    = (__half*)alloc((size_t)(NROWS + 64) * F_IN * sizeof(__half));
    float*  aggx   = (float*) alloc((size_t)(NROWS + 64) * F_IN * sizeof(float));

    const int eb = (E + 255) / 256;
    const int cb = (NTASK + 3) / 4;
    const int gb = (N_NODES + 3) / 4;
    const int mb = (NROWS + MROWS - 1) / MROWS;

    // ---- CSR build + fp16 convert
    const int zn = (NREP * N_NODES * 8) / 16;
    zero_kernel<<<(zn + 255) / 256, 256, 0, stream>>>((uint4*)packed, zn);
    deg_hist_conv_kernel<<<eb + cb, 256, 0, stream>>>(col, w, packed, posE, E, eb, x, xh);
    scan_kernel<<<1, 1024, 0, stream>>>(packed, rowptr, basep, dinv, N_NODES);
    fill_kernel<<<eb, 256, 0, stream>>>(row, col, w, dinv, basep, posE, edge_s, E);

    // ---- layer 1: 64-lane gather -> aggx, tiled MLP -> y2h
    gather64_kernel<false><<<gb, 256, 0, stream>>>(rowptr, edge_s, xh, nullptr, aggx, N_NODES);
    mlp_kernel<<<mb, 128, 0, stream>>>(aggx, W1, b1, W2, y2h);

    // ---- layer 2: 64-lane gather with fused tanh(acc + b2)
    gather64_kernel<true><<<gb, 256, 0, stream>>>(rowptr, edge_s, y2h, b2, out, N_NODES);
}

// Round 12
// 153.460 us; speedup vs baseline: 1.0464x; 1.0464x over previous
//
#include <hip/hip_runtime.h>
#include <hip/hip_fp16.h>

#define T_DIM   12
#define N_NODES 10000
#define F_IN    32
#define H_DIM   64
#define NCH     3            // t-chunks
#define TC      4            // timesteps per chunk
#define CHROW   (TC * F_IN)  // fp16/fp32 elements per node per chunk = 128
#define NGRP    (N_NODES / 16)
#define NTASK   (NCH * NGRP)
#define NROWS   (NCH * N_NODES * TC)  // 120000 (n,t) rows
#define MROWS   128                   // rows per mlp block
#define NREP    4                     // atomic replicas per node
#define PER     ((N_NODES + 1023) / 1024)   // compile-time: 10

#define CNT_SHIFT 40
#define FIX_SCALE 1048576.0f          // 2^20
#define FIX_MASK  ((1ull << CNT_SHIFT) - 1)

// ------------------------------------------------ zero packed counters (4 replicas)
__global__ void zero_kernel(uint4* __restrict__ p, int n16) {
    int i = blockIdx.x * blockDim.x + threadIdx.x;
    if (i < n16) p[i] = make_uint4(0, 0, 0, 0);
}

// ------------------------------------------------ fused: replicated packed degree+count atomic
// (1 atomic/edge to packed[(e&3)*N + c]; return value = within-replica position) and
// x fp32 [t][n][f] -> xh fp16 chunked convert
__global__ void deg_hist_conv_kernel(const int* __restrict__ col,
                                     const float* __restrict__ w,
                                     unsigned long long* __restrict__ packed,
                                     unsigned int* __restrict__ posE, int E, int eb,
                                     const float* __restrict__ x,
                                     __half* __restrict__ xh) {
    int b = blockIdx.x;
    if (b < eb) {
        int e = b * 256 + threadIdx.x;
        if (e >= E) return;
        int c = col[e];
        unsigned long long fx = (unsigned long long)(w[e] * FIX_SCALE + 0.5f);
        unsigned long long old =
            atomicAdd(&packed[(size_t)(e & (NREP - 1)) * N_NODES + c], (1ull << CNT_SHIFT) | fx);
        posE[e] = (unsigned int)(old >> CNT_SHIFT);
    } else {
        int task = (b - eb) * 4 + (threadIdx.x >> 6);
        if (task >= NTASK) return;
        int l  = threadIdx.x & 63;
        int ch = task / NGRP;
        int ng = task - ch * NGRP;
        int n  = ng * 16 + (l >> 2);
        int t  = ch * TC + (l & 3);
        const float4* xp = (const float4*)(x + ((size_t)t * N_NODES + n) * F_IN);
        union { uint32_t u[16]; uint4 q[4]; } pk;
#pragma unroll
        for (int i = 0; i < 8; i++) {
            float4 v = xp[i];
            __half2 h0 = __floats2half2_rn(v.x, v.y);
            __half2 h1 = __floats2half2_rn(v.z, v.w);
            pk.u[2 * i]     = *(uint32_t*)&h0;
            pk.u[2 * i + 1] = *(uint32_t*)&h1;
        }
        uint4* dp = (uint4*)(xh + ((size_t)ch * N_NODES * TC + ng * 64 + l) * F_IN);
#pragma unroll
        for (int i = 0; i < 4; i++) dp[i] = pk.q[i];
    }
}

// ------------------------------------------------ single-block scan: 4 replicas -> rowptr,
// per-replica bases base[r][c], dinv. PER is compile-time; cpack fully static -> registers.
__global__ __launch_bounds__(1024) void scan_kernel(const unsigned long long* __restrict__ packed,
                                                    int* __restrict__ rowptr,
                                                    int* __restrict__ base,
                                                    float* __restrict__ dinv, int n) {
    __shared__ int part[1024];
    int tid = threadIdx.x;
    int bidx = tid * PER;
    unsigned int cpack[PER];     // per-node 4 counts, 8 bits each — static indexing only
    int s = 0;
#pragma unroll
    for (int i = 0; i < PER; i++) {
        int idx = bidx + i;
        unsigned int cp = 0;
        if (idx < n) {
            unsigned long long p0 = packed[idx];
            unsigned long long p1 = packed[(size_t)N_NODES + idx];
            unsigned long long p2 = packed[(size_t)2 * N_NODES + idx];
            unsigned long long p3 = packed[(size_t)3 * N_NODES + idx];
            unsigned int c0 = (unsigned int)(p0 >> CNT_SHIFT);
            unsigned int c1 = (unsigned int)(p1 >> CNT_SHIFT);
            unsigned int c2 = (unsigned int)(p2 >> CNT_SHIFT);
            unsigned int c3 = (unsigned int)(p3 >> CNT_SHIFT);
            cp = c0 | (c1 << 8) | (c2 << 16) | (c3 << 24);
            s += (int)(c0 + c1 + c2 + c3);
            float deg = (float)((p0 & FIX_MASK) + (p1 & FIX_MASK) + (p2 & FIX_MASK) + (p3 & FIX_MASK))
                        * (1.0f / FIX_SCALE);
            dinv[idx] = deg > 0.f ? rsqrtf(deg) : 0.f;
        }
        cpack[i] = cp;
    }
    part[tid] = s;
    __syncthreads();
    for (int off = 1; off < 1024; off <<= 1) {
        int v = 0;
        if (tid >= off) v = part[tid - off];
        __syncthreads();
        if (tid >= off) part[tid] += v;
        __syncthreads();
    }
    int run = (tid == 0) ? 0 : part[tid - 1];
#pragma unroll
    for (int i = 0; i < PER; i++) {
        int idx = bidx + i;
        if (idx < n) {
            unsigned int cp = cpack[i];
            int c0 = cp & 255, c1 = (cp >> 8) & 255, c2 = (cp >> 16) & 255, c3 = cp >> 24;
            rowptr[idx] = run;
            base[idx]                 = run;
            base[N_NODES + idx]       = run + c0;
            base[2 * N_NODES + idx]   = run + c0 + c1;
            base[3 * N_NODES + idx]   = run + c0 + c1 + c2;
            run += c0 + c1 + c2 + c3;
        }
    }
    if (tid == 1023) rowptr[n] = part[1023];
}

// ------------------------------------------------ fill: ATOMIC-FREE bucket placement
__global__ void fill_kernel(const int* __restrict__ row,
                            const int* __restrict__ col,
                            const float* __restrict__ w,
                            const float* __restrict__ dinv,
                            const int* __restrict__ base,
                            const unsigned int* __restrict__ posE,
                            int2* __restrict__ edge_s, int E) {
    int e = blockIdx.x * blockDim.x + threadIdx.x;
    if (e >= E) return;
    int r = row[e];
    int c = col[e];
    float nw = dinv[r] * w[e] * dinv[c];
    int pos = base[(size_t)(e & (NREP - 1)) * N_NODES + c] + (int)posE[e];
    edge_s[pos] = make_int2(r, __float_as_int(nw));
}

// ------------------------------------------------ 64-lane-per-node single-pass gather.
// Two 32-lane halves split the edge list (stride 2), combine via shfl_xor(32).
// TANH=false: write fp32 chunked [ch][n][tc][f]. TANH=true: tanh(acc+bias) -> [t][n][f].
template <bool TANH>
__global__ __launch_bounds__(256) void gather64_kernel(const int* __restrict__ rowptr,
                                                       const int2* __restrict__ edge_s,
                                                       const __half* __restrict__ yh,
                                                       const float* __restrict__ bias,
                                                       float* __restrict__ outp, int n) {
    int c = blockIdx.x * 4 + (threadIdx.x >> 6);
    if (c >= n) return;
    int l    = threadIdx.x & 63;
    int half = l >> 5;
    int l32  = l & 31;          // tc = l32>>3, f-quad = l32&7 -> fp16 offset 4*l32

    int beg = rowptr[c], end = rowptr[c + 1];
    const __half* base = yh + 4 * l32;
    const size_t cstep = (size_t)N_NODES * CHROW;

    float4 a0 = {0.f, 0.f, 0.f, 0.f};
    float4 a1 = {0.f, 0.f, 0.f, 0.f};
    float4 a2 = {0.f, 0.f, 0.f, 0.f};

#pragma unroll 4
    for (int e = beg + half; e < end; e += 2) {
        int2 ed = edge_s[e];
        float nw = __int_as_float(ed.y);
        const __half* p = base + (size_t)ed.x * CHROW;
        uint2 u0 = *(const uint2*)(p);
        uint2 u1 = *(const uint2*)(p + cstep);
        uint2 u2 = *(const uint2*)(p + 2 * cstep);
        float2 f00 = __half22float2(*(__half2*)&u0.x), f01 = __half22float2(*(__half2*)&u0.y);
        float2 f10 = __half22float2(*(__half2*)&u1.x), f11 = __half22float2(*(__half2*)&u1.y);
        float2 f20 = __half22float2(*(__half2*)&u2.x), f21 = __half22float2(*(__half2*)&u2.y);
        a0.x = fmaf(f00.x, nw, a0.x); a0.y = fmaf(f00.y, nw, a0.y);
        a0.z = fmaf(f01.x, nw, a0.z); a0.w = fmaf(f01.y, nw, a0.w);
        a1.x = fmaf(f10.x, nw, a1.x); a1.y = fmaf(f10.y, nw, a1.y);
        a1.z = fmaf(f11.x, nw, a1.z); a1.w = fmaf(f11.y, nw, a1.w);
        a2.x = fmaf(f20.x, nw, a2.x); a2.y = fmaf(f20.y, nw, a2.y);
        a2.z = fmaf(f21.x, nw, a2.z); a2.w = fmaf(f21.y, nw, a2.w);
    }

    a0.x += __shfl_xor(a0.x, 32); a0.y += __shfl_xor(a0.y, 32);
    a0.z += __shfl_xor(a0.z, 32); a0.w += __shfl_xor(a0.w, 32);
    a1.x += __shfl_xor(a1.x, 32); a1.y += __shfl_xor(a1.y, 32);
    a1.z += __shfl_xor(a1.z, 32); a1.w += __shfl_xor(a1.w, 32);
    a2.x += __shfl_xor(a2.x, 32); a2.y += __shfl_xor(a2.y, 32);
    a2.z += __shfl_xor(a2.z, 32); a2.w += __shfl_xor(a2.w, 32);

    if (TANH) {
        float4 b4 = *(const float4*)(bias + 4 * (l32 & 7));
        if (half == 0) {
            a0.x = tanhf(a0.x + b4.x); a0.y = tanhf(a0.y + b4.y);
            a0.z = tanhf(a0.z + b4.z); a0.w = tanhf(a0.w + b4.w);
            a1.x = tanhf(a1.x + b4.x); a1.y = tanhf(a1.y + b4.y);
            a1.z = tanhf(a1.z + b4.z); a1.w = tanhf(a1.w + b4.w);
            int t0 = (l32 >> 3);
            float* op0 = outp + ((size_t)t0 * N_NODES + c) * F_IN + 4 * (l32 & 7);
            *(float4*)(op0)                               = a0;
            *(float4*)(op0 + (size_t)TC * N_NODES * F_IN) = a1;
        } else {
            a2.x = tanhf(a2.x + b4.x); a2.y = tanhf(a2.y + b4.y);
            a2.z = tanhf(a2.z + b4.z); a2.w = tanhf(a2.w + b4.w);
            int t2 = 2 * TC + (l32 >> 3);
            float* op2 = outp + ((size_t)t2 * N_NODES + c) * F_IN + 4 * (l32 & 7);
            *(float4*)op2 = a2;
        }
    } else {
        float* op = outp + (size_t)c * CHROW + 4 * l32;
        const size_t ostep = (size_t)N_NODES * CHROW;
        if (half == 0) {
            *(float4*)(op)         = a0;
            *(float4*)(op + ostep) = a1;
        } else {
            *(float4*)(op + 2 * ostep) = a2;
        }
    }
}

// ------------------------------------------------ fused MLP: register-blocked tile GEMM
__global__ __launch_bounds__(128) void mlp_kernel(const float* __restrict__ aggx,
                                                  const float* __restrict__ W1g,
                                                  const float* __restrict__ b1,
                                                  const float* __restrict__ W2g,
                                                  __half* __restrict__ y2h) {
    __shared__ float W1s[F_IN * H_DIM];
    __shared__ float W2s[H_DIM * F_IN];
    __shared__ float b1s[H_DIM];
    __shared__ float xs[MROWS][F_IN + 1];
    __shared__ float hs[MROWS][H_DIM + 1];

    int tid = threadIdx.x;
    for (int i = tid; i < F_IN * H_DIM; i += 128) { W1s[i] = W1g[i]; W2s[i] = W2g[i]; }
    if (tid < H_DIM) b1s[tid] = b1[tid];

    size_t row0 = (size_t)blockIdx.x * MROWS;
    const float4* src = (const float4*)(aggx + row0 * F_IN);
    for (int i = tid; i < MROWS * (F_IN / 4); i += 128) {
        float4 v = src[i];
        int r = i >> 3, q = (i & 7) * 4;
        xs[r][q + 0] = v.x; xs[r][q + 1] = v.y; xs[r][q + 2] = v.z; xs[r][q + 3] = v.w;
    }
    __syncthreads();

    int rg = tid >> 2;
    int cg = tid & 3;
    int r0 = 4 * rg;

    {
        int c0 = 16 * cg;
        float acc[4][16];
#pragma unroll
        for (int j = 0; j < 16; j++) {
            float b = b1s[c0 + j];
#pragma unroll
            for (int rr = 0; rr < 4; rr++) acc[rr][j] = b;
        }
#pragma unroll 8
        for (int k = 0; k < F_IN; k++) {
            float xr[4];
#pragma unroll
            for (int rr = 0; rr < 4; rr++) xr[rr] = xs[r0 + rr][k];
#pragma unroll
            for (int j = 0; j < 16; j++) {
                float wv = W1s[k * H_DIM + c0 + j];
#pragma unroll
                for (int rr = 0; rr < 4; rr++) acc[rr][j] = fmaf(xr[rr], wv, acc[rr][j]);
            }
        }
#pragma unroll
        for (int rr = 0; rr < 4; rr++)
#pragma unroll
            for (int j = 0; j < 16; j++)
                hs[r0 + rr][c0 + j] = fmaxf(acc[rr][j], 0.f);
    }
    __syncthreads();

    {
        int d0 = 8 * cg;
        float acc[4][8];
#pragma unroll
        for (int rr = 0; rr < 4; rr++)
#pragma unroll
            for (int j = 0; j < 8; j++) acc[rr][j] = 0.f;
#pragma unroll 8
        for (int k = 0; k < H_DIM; k++) {
            float hr[4];
#pragma unroll
            for (int rr = 0; rr < 4; rr++) hr[rr] = hs[r0 + rr][k];
#pragma unroll
            for (int j = 0; j < 8; j++) {
                float wv = W2s[k * F_IN + d0 + j];
#pragma unroll
                for (int rr = 0; rr < 4; rr++) acc[rr][j] = fmaf(hr[rr], wv, acc[rr][j]);
            }
        }
#pragma unroll
        for (int rr = 0; rr < 4; rr++) {
            union { uint32_t u[4]; uint4 q; } pk;
#pragma unroll
            for (int i = 0; i < 4; i++) {
                __half2 hh = __floats2half2_rn(acc[rr][2 * i], acc[rr][2 * i + 1]);
                pk.u[i] = *(uint32_t*)&hh;
            }
            *(uint4*)(y2h + (row0 + r0 + rr) * F_IN + d0) = pk.q;
        }
    }
}

// ----------------------------------------------------------------
extern "C" void kernel_launch(void* const* d_in, const int* in_sizes, int n_in,
                              void* d_out, int out_size, void* d_ws, size_t ws_size,
                              hipStream_t stream) {
    const float* x  = (const float*)d_in[0];
    const int*   ei = (const int*)d_in[1];
    const float* w  = (const float*)d_in[2];
    // d_in[3] = missing_mask (unused)
    const float* W1 = (const float*)d_in[4];
    const float* b1 = (const float*)d_in[5];
    const float* W2 = (const float*)d_in[6];
    const float* b2 = (const float*)d_in[7];
    float* out = (float*)d_out;

    const int E = in_sizes[1] / 2;
    const int* row = ei;
    const int* col = ei + E;

    char* ws = (char*)d_ws;
    size_t off = 0;
    auto alloc = [&](size_t bytes) { void* p = ws + off; off += (bytes + 255) & ~(size_t)255; return p; };
    unsigned long long* packed = (unsigned long long*)alloc((size_t)NREP * N_NODES * sizeof(unsigned long long));
    unsigned int* posE = (unsigned int*)alloc((size_t)E * sizeof(unsigned int));
    int*    rowptr = (int*)   alloc((N_NODES + 1) * sizeof(int));
    int*    basep  = (int*)   alloc((size_t)NREP * N_NODES * sizeof(int));
    float*  dinv   = (float*) alloc(N_NODES * sizeof(float));
    int2*   edge_s = (int2*)  alloc((size_t)E * sizeof(int2));
    __half* xh     = (__half*)alloc((size_t)NROWS * F_IN * sizeof(__half));
    __half* y2h    = (__half*)alloc((size_t)(NROWS + 64) * F_IN * sizeof(__half));
    float*  aggx   = (float*) alloc((size_t)(NROWS + 64) * F_IN * sizeof(float));

    const int eb = (E + 255) / 256;
    const int cb = (NTASK + 3) / 4;
    const int gb = (N_NODES + 3) / 4;
    const int mb = (NROWS + MROWS - 1) / MROWS;

    // ---- CSR build + fp16 convert
    const int zn = (NREP * N_NODES * 8) / 16;
    zero_kernel<<<(zn + 255) / 256, 256, 0, stream>>>((uint4*)packed, zn);
    deg_hist_conv_kernel<<<eb + cb, 256, 0, stream>>>(col, w, packed, posE, E, eb, x, xh);
    scan_kernel<<<1, 1024, 0, stream>>>(packed, rowptr, basep, dinv, N_NODES);
    fill_kernel<<<eb, 256, 0, stream>>>(row, col, w, dinv, basep, posE, edge_s, E);

    // ---- layer 1: 64-lane gather -> aggx, tiled MLP -> y2h
    gather64_kernel<false><<<gb, 256, 0, stream>>>(rowptr, edge_s, xh, nullptr, aggx, N_NODES);
    mlp_kernel<<<mb, 128, 0, stream>>>(aggx, W1, b1, W2, y2h);

    // ---- layer 2: 64-lane gather with fused tanh(acc + b2)
    gather64_kernel<true><<<gb, 256, 0, stream>>>(rowptr, edge_s, y2h, b2, out, N_NODES);
}

// Round 13
// 136.372 us; speedup vs baseline: 1.1775x; 1.1253x over previous
//
#include <hip/hip_runtime.h>
#include <hip/hip_fp16.h>

#define T_DIM   12
#define N_NODES 10000
#define F_IN    32
#define H_DIM   64
#define NCH     3            // t-chunks
#define TC      4            // timesteps per chunk
#define CHROW   (TC * F_IN)  // fp16/fp32 elements per node per chunk = 128
#define NGRP    (N_NODES / 16)
#define NTASK   (NCH * NGRP)
#define NROWS   (NCH * N_NODES * TC)  // 120000 (n,t) rows
#define MROWS   128                   // rows per mlp block

#define CNT_SHIFT 40
#define FIX_SCALE 1048576.0f          // 2^20
#define FIX_MASK  ((1ull << CNT_SHIFT) - 1)

// ------------------------------------------------ zero packed deg/cnt
__global__ void zero_kernel(uint4* __restrict__ p, int n16) {
    int i = blockIdx.x * blockDim.x + threadIdx.x;
    if (i < n16) p[i] = make_uint4(0, 0, 0, 0);
}

// ------------------------------------------------ fused: packed degree+count atomic (one 64-bit
// atomic per edge; return value = within-bucket position) and x fp32 -> xh fp16 chunked convert.
// Conv stores are LDS-staged so every global store instruction writes 1 KB of WHOLE cachelines
// (direct per-lane 16B stores at stride 64B caused 3x HBM write amplification).
__global__ void deg_hist_conv_kernel(const int* __restrict__ col,
                                     const float* __restrict__ w,
                                     unsigned long long* __restrict__ packed,
                                     unsigned int* __restrict__ posE, int E, int eb,
                                     const float* __restrict__ x,
                                     __half* __restrict__ xh) {
    __shared__ __align__(16) unsigned char lbuf[4][64 * 64];   // 16 KB: per-wave 4 KB
    int b = blockIdx.x;
    if (b < eb) {
        int e = b * 256 + threadIdx.x;
        if (e >= E) return;
        int c = col[e];
        unsigned long long fx = (unsigned long long)(w[e] * FIX_SCALE + 0.5f);
        unsigned long long old = atomicAdd(&packed[c], (1ull << CNT_SHIFT) | fx);
        posE[e] = (unsigned int)(old >> CNT_SHIFT);
    } else {
        int task = (b - eb) * 4 + (threadIdx.x >> 6);
        int wv = threadIdx.x >> 6;
        int l  = threadIdx.x & 63;
        bool active = task < NTASK;
        size_t rowbase = 0;
        if (active) {
            int ch = task / NGRP;
            int ng = task - ch * NGRP;
            int n  = ng * 16 + (l >> 2);
            int t  = ch * TC + (l & 3);
            const float4* xp = (const float4*)(x + ((size_t)t * N_NODES + n) * F_IN);
            uint4* ls = (uint4*)(lbuf[wv] + l * 64);
#pragma unroll
            for (int i = 0; i < 4; i++) {
                float4 v0 = xp[2 * i];
                float4 v1 = xp[2 * i + 1];
                __half2 h0 = __floats2half2_rn(v0.x, v0.y);
                __half2 h1 = __floats2half2_rn(v0.z, v0.w);
                __half2 h2 = __floats2half2_rn(v1.x, v1.y);
                __half2 h3 = __floats2half2_rn(v1.z, v1.w);
                uint4 q;
                q.x = *(uint32_t*)&h0; q.y = *(uint32_t*)&h1;
                q.z = *(uint32_t*)&h2; q.w = *(uint32_t*)&h3;
                ls[i] = q;
            }
            rowbase = ((size_t)ch * N_NODES * TC + (size_t)ng * 64) * F_IN;  // fp16 elems, wave-uniform
        }
        __syncthreads();
        if (active) {
            const uint4* ls = (const uint4*)lbuf[wv];
            uint4* gdst = (uint4*)(xh + rowbase);
#pragma unroll
            for (int i = 0; i < 4; i++)
                gdst[i * 64 + l] = ls[i * 64 + l];   // 64 lanes x consecutive 16B = 1KB/inst
        }
    }
}

// ------------------------------------------------ single-block scan: packed -> rowptr + dinv
__global__ __launch_bounds__(1024) void scan_kernel(const unsigned long long* __restrict__ packed,
                                                    int* __restrict__ rowptr,
                                                    float* __restrict__ dinv, int n) {
    __shared__ int part[1024];
    int tid = threadIdx.x;
    const int per = (n + 1023) / 1024;
    int base = tid * per;
    int s = 0;
    for (int i = 0; i < per; i++) {
        int idx = base + i;
        if (idx < n) {
            unsigned long long p = packed[idx];
            s += (int)(p >> CNT_SHIFT);
            float deg = (float)(p & FIX_MASK) * (1.0f / FIX_SCALE);
            dinv[idx] = deg > 0.f ? rsqrtf(deg) : 0.f;
        }
    }
    part[tid] = s;
    __syncthreads();
    for (int off = 1; off < 1024; off <<= 1) {
        int v = 0;
        if (tid >= off) v = part[tid - off];
        __syncthreads();
        if (tid >= off) part[tid] += v;
        __syncthreads();
    }
    int run = (tid == 0) ? 0 : part[tid - 1];
    for (int i = 0; i < per; i++) {
        int idx = base + i;
        if (idx < n) {
            rowptr[idx] = run;
            run += (int)(packed[idx] >> CNT_SHIFT);
        }
    }
    if (tid == 1023) rowptr[n] = part[1023];
}

// ------------------------------------------------ fill: ATOMIC-FREE bucket placement via posE
__global__ void fill_kernel(const int* __restrict__ row,
                            const int* __restrict__ col,
                            const float* __restrict__ w,
                            const float* __restrict__ dinv,
                            const int* __restrict__ rowptr,
                            const unsigned int* __restrict__ posE,
                            int2* __restrict__ edge_s, int E) {
    int e = blockIdx.x * blockDim.x + threadIdx.x;
    if (e >= E) return;
    int r = row[e];
    int c = col[e];
    float nw = dinv[r] * w[e] * dinv[c];
    int pos = rowptr[c] + (int)posE[e];
    edge_s[pos] = make_int2(r, __float_as_int(nw));
}

// ------------------------------------------------ 64-lane-per-node single-pass gather.
// Two 32-lane halves split the edge list (stride 2), combine via shfl_xor(32).
// TANH=false: write fp32 chunked [ch][n][tc][f]. TANH=true: tanh(acc+bias) -> [t][n][f].
template <bool TANH>
__global__ __launch_bounds__(256) void gather64_kernel(const int* __restrict__ rowptr,
                                                       const int2* __restrict__ edge_s,
                                                       const __half* __restrict__ yh,
                                                       const float* __restrict__ bias,
                                                       float* __restrict__ outp, int n) {
    int c = blockIdx.x * 4 + (threadIdx.x >> 6);
    if (c >= n) return;
    int l    = threadIdx.x & 63;
    int half = l >> 5;
    int l32  = l & 31;          // tc = l32>>3, f-quad = l32&7 -> fp16 offset 4*l32

    int beg = rowptr[c], end = rowptr[c + 1];
    const __half* base = yh + 4 * l32;
    const size_t cstep = (size_t)N_NODES * CHROW;

    float4 a0 = {0.f, 0.f, 0.f, 0.f};
    float4 a1 = {0.f, 0.f, 0.f, 0.f};
    float4 a2 = {0.f, 0.f, 0.f, 0.f};

#pragma unroll 4
    for (int e = beg + half; e < end; e += 2) {
        int2 ed = edge_s[e];
        float nw = __int_as_float(ed.y);
        const __half* p = base + (size_t)ed.x * CHROW;
        uint2 u0 = *(const uint2*)(p);
        uint2 u1 = *(const uint2*)(p + cstep);
        uint2 u2 = *(const uint2*)(p + 2 * cstep);
        float2 f00 = __half22float2(*(__half2*)&u0.x), f01 = __half22float2(*(__half2*)&u0.y);
        float2 f10 = __half22float2(*(__half2*)&u1.x), f11 = __half22float2(*(__half2*)&u1.y);
        float2 f20 = __half22float2(*(__half2*)&u2.x), f21 = __half22float2(*(__half2*)&u2.y);
        a0.x = fmaf(f00.x, nw, a0.x); a0.y = fmaf(f00.y, nw, a0.y);
        a0.z = fmaf(f01.x, nw, a0.z); a0.w = fmaf(f01.y, nw, a0.w);
        a1.x = fmaf(f10.x, nw, a1.x); a1.y = fmaf(f10.y, nw, a1.y);
        a1.z = fmaf(f11.x, nw, a1.z); a1.w = fmaf(f11.y, nw, a1.w);
        a2.x = fmaf(f20.x, nw, a2.x); a2.y = fmaf(f20.y, nw, a2.y);
        a2.z = fmaf(f21.x, nw, a2.z); a2.w = fmaf(f21.y, nw, a2.w);
    }

    a0.x += __shfl_xor(a0.x, 32); a0.y += __shfl_xor(a0.y, 32);
    a0.z += __shfl_xor(a0.z, 32); a0.w += __shfl_xor(a0.w, 32);
    a1.x += __shfl_xor(a1.x, 32); a1.y += __shfl_xor(a1.y, 32);
    a1.z += __shfl_xor(a1.z, 32); a1.w += __shfl_xor(a1.w, 32);
    a2.x += __shfl_xor(a2.x, 32); a2.y += __shfl_xor(a2.y, 32);
    a2.z += __shfl_xor(a2.z, 32); a2.w += __shfl_xor(a2.w, 32);

    if (TANH) {
        float4 b4 = *(const float4*)(bias + 4 * (l32 & 7));
        if (half == 0) {
            a0.x = tanhf(a0.x + b4.x); a0.y = tanhf(a0.y + b4.y);
            a0.z = tanhf(a0.z + b4.z); a0.w = tanhf(a0.w + b4.w);
            a1.x = tanhf(a1.x + b4.x); a1.y = tanhf(a1.y + b4.y);
            a1.z = tanhf(a1.z + b4.z); a1.w = tanhf(a1.w + b4.w);
            int t0 = (l32 >> 3);
            float* op0 = outp + ((size_t)t0 * N_NODES + c) * F_IN + 4 * (l32 & 7);
            *(float4*)(op0)                               = a0;
            *(float4*)(op0 + (size_t)TC * N_NODES * F_IN) = a1;
        } else {
            a2.x = tanhf(a2.x + b4.x); a2.y = tanhf(a2.y + b4.y);
            a2.z = tanhf(a2.z + b4.z); a2.w = tanhf(a2.w + b4.w);
            int t2 = 2 * TC + (l32 >> 3);
            float* op2 = outp + ((size_t)t2 * N_NODES + c) * F_IN + 4 * (l32 & 7);
            *(float4*)op2 = a2;
        }
    } else {
        float* op = outp + (size_t)c * CHROW + 4 * l32;
        const size_t ostep = (size_t)N_NODES * CHROW;
        if (half == 0) {
            *(float4*)(op)         = a0;
            *(float4*)(op + ostep) = a1;
        } else {
            *(float4*)(op + 2 * ostep) = a2;
        }
    }
}

// ------------------------------------------------ fused MLP: register-blocked tile GEMM
__global__ __launch_bounds__(128) void mlp_kernel(const float* __restrict__ aggx,
                                                  const float* __restrict__ W1g,
                                                  const float* __restrict__ b1,
                                                  const float* __restrict__ W2g,
                                                  __half* __restrict__ y2h) {
    __shared__ float W1s[F_IN * H_DIM];
    __shared__ float W2s[H_DIM * F_IN];
    __shared__ float b1s[H_DIM];
    __shared__ float xs[MROWS][F_IN + 1];
    __shared__ float hs[MROWS][H_DIM + 1];

    int tid = threadIdx.x;
    for (int i = tid; i < F_IN * H_DIM; i += 128) { W1s[i] = W1g[i]; W2s[i] = W2g[i]; }
    if (tid < H_DIM) b1s[tid] = b1[tid];

    size_t row0 = (size_t)blockIdx.x * MROWS;
    const float4* src = (const float4*)(aggx + row0 * F_IN);
    for (int i = tid; i < MROWS * (F_IN / 4); i += 128) {
        float4 v = src[i];
        int r = i >> 3, q = (i & 7) * 4;
        xs[r][q + 0] = v.x; xs[r][q + 1] = v.y; xs[r][q + 2] = v.z; xs[r][q + 3] = v.w;
    }
    __syncthreads();

    int rg = tid >> 2;
    int cg = tid & 3;
    int r0 = 4 * rg;

    {
        int c0 = 16 * cg;
        float acc[4][16];
#pragma unroll
        for (int j = 0; j < 16; j++) {
            float b = b1s[c0 + j];
#pragma unroll
            for (int rr = 0; rr < 4; rr++) acc[rr][j] = b;
        }
#pragma unroll 8
        for (int k = 0; k < F_IN; k++) {
            float xr[4];
#pragma unroll
            for (int rr = 0; rr < 4; rr++) xr[rr] = xs[r0 + rr][k];
#pragma unroll
            for (int j = 0; j < 16; j++) {
                float wv = W1s[k * H_DIM + c0 + j];
#pragma unroll
                for (int rr = 0; rr < 4; rr++) acc[rr][j] = fmaf(xr[rr], wv, acc[rr][j]);
            }
        }
#pragma unroll
        for (int rr = 0; rr < 4; rr++)
#pragma unroll
            for (int j = 0; j < 16; j++)
                hs[r0 + rr][c0 + j] = fmaxf(acc[rr][j], 0.f);
    }
    __syncthreads();

    {
        int d0 = 8 * cg;
        float acc[4][8];
#pragma unroll
        for (int rr = 0; rr < 4; rr++)
#pragma unroll
            for (int j = 0; j < 8; j++) acc[rr][j] = 0.f;
#pragma unroll 8
        for (int k = 0; k < H_DIM; k++) {
            float hr[4];
#pragma unroll
            for (int rr = 0; rr < 4; rr++) hr[rr] = hs[r0 + rr][k];
#pragma unroll
            for (int j = 0; j < 8; j++) {
                float wv = W2s[k * F_IN + d0 + j];
#pragma unroll
                for (int rr = 0; rr < 4; rr++) acc[rr][j] = fmaf(hr[rr], wv, acc[rr][j]);
            }
        }
#pragma unroll
        for (int rr = 0; rr < 4; rr++) {
            union { uint32_t u[4]; uint4 q; } pk;
#pragma unroll
            for (int i = 0; i < 4; i++) {
                __half2 hh = __floats2half2_rn(acc[rr][2 * i], acc[rr][2 * i + 1]);
                pk.u[i] = *(uint32_t*)&hh;
            }
            *(uint4*)(y2h + (row0 + r0 + rr) * F_IN + d0) = pk.q;
        }
    }
}

// ----------------------------------------------------------------
extern "C" void kernel_launch(void* const* d_in, const int* in_sizes, int n_in,
                              void* d_out, int out_size, void* d_ws, size_t ws_size,
                              hipStream_t stream) {
    const float* x  = (const float*)d_in[0];
    const int*   ei = (const int*)d_in[1];
    const float* w  = (const float*)d_in[2];
    // d_in[3] = missing_mask (unused)
    const float* W1 = (const float*)d_in[4];
    const float* b1 = (const float*)d_in[5];
    const float* W2 = (const float*)d_in[6];
    const float* b2 = (const float*)d_in[7];
    float* out = (float*)d_out;

    const int E = in_sizes[1] / 2;
    const int* row = ei;
    const int* col = ei + E;

    char* ws = (char*)d_ws;
    size_t off = 0;
    auto alloc = [&](size_t bytes) { void* p = ws + off; off += (bytes + 255) & ~(size_t)255; return p; };
    unsigned long long* packed = (unsigned long long*)alloc(N_NODES * sizeof(unsigned long long));
    unsigned int* posE = (unsigned int*)alloc((size_t)E * sizeof(unsigned int));
    int*    rowptr = (int*)   alloc((N_NODES + 1) * sizeof(int));
    float*  dinv   = (float*) alloc(N_NODES * sizeof(float));
    int2*   edge_s = (int2*)  alloc((size_t)E * sizeof(int2));
    __half* xh     = (__half*)alloc((size_t)NROWS * F_IN * sizeof(__half));
    __half* y2h    = (__half*)alloc((size_t)(NROWS + 64) * F_IN * sizeof(__half));
    float*  aggx   = (float*) alloc((size_t)(NROWS + 64) * F_IN * sizeof(float));

    const int eb = (E + 255) / 256;
    const int cb = (NTASK + 3) / 4;
    const int gb = (N_NODES + 3) / 4;
    const int mb = (NROWS + MROWS - 1) / MROWS;

    // ---- CSR build + fp16 convert
    const int zn = (N_NODES * 8) / 16;
    zero_kernel<<<(zn + 255) / 256, 256, 0, stream>>>((uint4*)packed, zn);
    deg_hist_conv_kernel<<<eb + cb, 256, 0, stream>>>(col, w, packed, posE, E, eb, x, xh);
    scan_kernel<<<1, 1024, 0, stream>>>(packed, rowptr, dinv, N_NODES);
    fill_kernel<<<eb, 256, 0, stream>>>(row, col, w, dinv, rowptr, posE, edge_s, E);

    // ---- layer 1: 64-lane gather -> aggx, tiled MLP -> y2h
    gather64_kernel<false><<<gb, 256, 0, stream>>>(rowptr, edge_s, xh, nullptr, aggx, N_NODES);
    mlp_kernel<<<mb, 128, 0, stream>>>(aggx, W1, b1, W2, y2h);

    // ---- layer 2: 64-lane gather with fused tanh(acc + b2)
    gather64_kernel<true><<<gb, 256, 0, stream>>>(rowptr, edge_s, y2h, b2, out, N_NODES);
}